// Round 9
// baseline (7075.019 us; speedup 1.0000x reference)
//
#include <hip/hip_runtime.h>
#include <hip/hip_bf16.h>
#include <cstdint>
#include <cstddef>

#define H   1024
#define D   80
#define DP  96          // D padded to multiple of 32 (zero-padded)
#define T   512
#define B   64
#define NG  32          // gate rows per block (4 gates x 8 hidden units)
#define KP  1032        // LDS row stride for Whh slice (+8 bf16 pad)
#define KPI 104         // LDS row stride for Wih slice

typedef __attribute__((ext_vector_type(8))) short bf16x8;   // 8 bf16 (MFMA A/B frag)
typedef __attribute__((ext_vector_type(4))) float f32x4;    // MFMA C/D frag
typedef __attribute__((ext_vector_type(4))) unsigned int u32x4;

// bf16 +inf replicated: h = o*tanh(c) in [-1,1] can NEVER produce this pattern.
#define SENT64 0x7F807F807F807F80ull

// ws layout
#define HBUF_ELEMS ((size_t)2 * (T + 1) * B * H)            // bf16 h history, slot 0 = h_{-1}=0
#define HBUF_BYTES (HBUF_ELEMS * 2)
#define XS_ELEMS   ((size_t)T * B * DP)                     // bf16 teacher-forced inputs (padded)
#define XS_BYTES   (XS_ELEMS * 2)
#define WOUT_ELEMS ((size_t)2 * D * H)                      // bf16 W_out both decoders
#define WOUT_BYTES (WOUT_ELEMS * 2)
#define NFLAG      256                                       // completion flags (final barrier only)

__device__ __forceinline__ unsigned short f2bf(float x) {
    unsigned int u = __float_as_uint(x);
    unsigned int r = (u + 0x7FFFu + ((u >> 16) & 1u)) >> 16;   // RNE
    return (unsigned short)r;
}

// overflow-safe fast tanh: 2*sigmoid(2x)-1 (validated rounds 5-8, absmax unchanged)
__device__ __forceinline__ float fast_tanh(float x) {
    return 2.f / (1.f + __expf(-2.f * x)) - 1.f;
}

// agent-scope (coherence-point) 8-byte store/load: sc1 path, bypasses L1/L2.
__device__ __forceinline__ void coh_store8(unsigned long long* p, unsigned long long v) {
    __hip_atomic_store(p, v, __ATOMIC_RELAXED, __HIP_MEMORY_SCOPE_AGENT);
}
__device__ __forceinline__ unsigned long long coh_load8(const unsigned long long* p) {
    return __hip_atomic_load(p, __ATOMIC_RELAXED, __HIP_MEMORY_SCOPE_AGENT);
}

// ---- prep: x0 = input[T-1] @ W_in^T + b_in ----
__global__ void prep_x0(const float* __restrict__ inp, const float* __restrict__ Win,
                        const float* __restrict__ bin, unsigned short* __restrict__ xs)
{
    int o = blockIdx.x;                // 0 .. B*D-1
    int b = o / D, d = o % D;
    int lane = threadIdx.x;
    const float* irow = inp + ((size_t)(T - 1) * B + b) * H;
    const float* wrow = Win + (size_t)d * H;
    float s = 0.f;
    for (int k = lane; k < H; k += 64) s += irow[k] * wrow[k];
    for (int off = 32; off > 0; off >>= 1) s += __shfl_down(s, off, 64);
    if (lane == 0) xs[b * DP + d] = f2bf(s + bin[d]);
}

// ---- prep: xs[t] = target[t-1] (t>=1), zero pads ----
__global__ void prep_xs(const float* __restrict__ tgt, unsigned short* __restrict__ xs)
{
    int idx = blockIdx.x * 256 + threadIdx.x;
    if (idx >= T * B * DP) return;
    int t = idx / (B * DP);
    int r = idx % (B * DP);
    int b = r / DP, d = r % DP;
    if (d >= D) { xs[idx] = 0; return; }
    if (t == 0) return;
    xs[idx] = f2bf(tgt[((size_t)(t - 1) * B + b) * D + d]);
}

// ---- prep: fill hbuf slots 1..T (both decoders) with the sentinel pattern.
// Plain stores; the dispatch-boundary release writes L2 back to the MALL, so
// lstm_main's agent-scope loads see the sentinel before any producer store.
__global__ void prep_sent(u32x4* __restrict__ hbuf16)
{
    // per decoder: slots 1..T  ->  T*B*H shorts = T*B*H/8 16B-chunks
    const size_t perdec = (size_t)T * B * H / 8;        // 4,194,304 chunks
    const u32x4 s4 = {0x7F807F80u, 0x7F807F80u, 0x7F807F80u, 0x7F807F80u};
    for (size_t p = (size_t)blockIdx.x * 256 + threadIdx.x;
         p < 2 * perdec; p += (size_t)gridDim.x * 256) {
        size_t dec = p / perdec, r = p % perdec;
        hbuf16[(dec * (T + 1) + 1) * (B * H / 8) + r] = s4;
    }
}

// ---- prep: W_out->bf16, zero h slot 0, zero flags ----
__global__ void prep_misc(const float* __restrict__ fWout, const float* __restrict__ bWout,
                          unsigned short* __restrict__ woutbf, unsigned short* __restrict__ hbuf,
                          unsigned int* __restrict__ flags)
{
    int idx = blockIdx.x * 256 + threadIdx.x;
    const int NW = 2 * D * H;
    const int NZ = 2 * B * H;
    if (idx < NW) {
        int dec = idx / (D * H); int rr = idx % (D * H);
        woutbf[idx] = f2bf((dec ? bWout : fWout)[rr]);
    } else if (idx < NW + NZ) {
        int z = idx - NW;
        int dec = z / (B * H); int rr = z % (B * H);
        hbuf[(size_t)dec * (T + 1) * B * H + rr] = 0;
    } else if (idx < NW + NZ + NFLAG) {
        flags[idx - NW - NZ] = 0;
    }
}

// ---- main persistent kernel: 256 blocks x 256 threads (1 block/CU) ----
// Sync design: NO per-step flags. Producers fire sc1 stores and move on.
// Consumers spin on the h DATA itself (clustered 64x8B agent loads) until no
// fragment equals the sentinel. Detection and data transfer are one leg.
__global__ void __launch_bounds__(256, 1)
lstm_main(unsigned short* __restrict__ hbuf,
          const unsigned short* __restrict__ xs,
          const unsigned short* __restrict__ woutbf,
          unsigned int* __restrict__ flags,
          const float* __restrict__ fWih, const float* __restrict__ fWhh, const float* __restrict__ fbias,
          const float* __restrict__ bWih, const float* __restrict__ bWhh, const float* __restrict__ bbias,
          const float* __restrict__ fbout, const float* __restrict__ bbout,
          float* __restrict__ out)
{
    const int bid  = blockIdx.x;
    const int dec  = bid >> 7;          // 0 = fwd, 1 = bwd
    const int blk  = bid & 127;
    const int u0   = blk << 3;          // first of 8 owned hidden units
    const int tid  = threadIdx.x;
    const int wave = tid >> 6;
    const int lane = tid & 63;
    const int l15  = lane & 15;
    const int quad = lane >> 4;
    const int koff = quad * 8;

    __shared__ unsigned short sWhh[NG][KP];    // 66 KB
    __shared__ unsigned short sWih[NG][KPI];   // 6.5 KB
    __shared__ float sBias[NG];
    __shared__ float sG[B][33];
    __shared__ float sC[B][8];
    __shared__ bf16x8 sH[B];                   // packed h slice for vector publish

    const float* Wih  = dec ? bWih  : fWih;
    const float* Whh  = dec ? bWhh  : fWhh;
    const float* bias = dec ? bbias : fbias;

    for (int e = tid; e < NG * H; e += 256) {
        int n = e >> 10, k = e & (H - 1);
        int row = (n >> 3) * H + u0 + (n & 7);
        sWhh[n][k] = f2bf(Whh[(size_t)row * H + k]);
    }
    for (int e = tid; e < NG * KPI; e += 256) {
        int n = e / KPI, dd = e % KPI;
        int row = (n >> 3) * H + u0 + (n & 7);
        sWih[n][dd] = (dd < D) ? f2bf(Wih[(size_t)row * D + dd]) : 0;
    }
    if (tid < NG) {
        int row = (tid >> 3) * H + u0 + (tid & 7);
        sBias[tid] = bias[row];
    }
    for (int e = tid; e < B * 8; e += 256) sC[e >> 3][e & 7] = 0.f;
    __syncthreads();

    const int m = wave * 16 + l15;   // batch row this lane loads for A-frags
    unsigned int* myflag = flags + bid;

    union FragU { unsigned long long q[2]; bf16x8 v; };

    for (int t = 0; t < T; ++t) {
        // 4 accumulator chains: even/odd k x (units 0-7 / 8-15 columns)
        f32x4 acc0e = {0.f,0.f,0.f,0.f}, acc0o = {0.f,0.f,0.f,0.f};
        f32x4 acc1e = {0.f,0.f,0.f,0.f}, acc1o = {0.f,0.f,0.f,0.f};

        // x_t @ Wih^T first — independent of h_t, overlaps producer store flight
        const unsigned short* xrow = xs + ((size_t)t * B + m) * DP;
        #pragma unroll
        for (int kb = 0; kb < DP / 32; ++kb) {
            bf16x8 a  = *(const bf16x8*)(xrow + kb * 32 + koff);
            bf16x8 b0 = *(const bf16x8*)(&sWih[l15][kb * 32 + koff]);
            bf16x8 b1 = *(const bf16x8*)(&sWih[16 + l15][kb * 32 + koff]);
            acc0e = __builtin_amdgcn_mfma_f32_16x16x32_bf16(a, b0, acc0e, 0, 0, 0);
            acc1e = __builtin_amdgcn_mfma_f32_16x16x32_bf16(a, b1, acc1e, 0, 0, 0);
        }

        // SENTINEL POLL: clustered 64x8B agent-scope loads of this lane's h row
        // quarter; valid iff no u64 equals the sentinel. 8B atomic stores can't
        // tear, per-u64 validation makes partial arrival safe. t=0 reads the
        // zeroed slot (0 != SENT) and exits immediately. No barrier needed:
        // each wave polls exactly the fragments it will consume.
        FragU A[32];
        {
            const unsigned long long* hq = (const unsigned long long*)
                (hbuf + ((size_t)(dec * (T + 1) + t) * B + m) * H + koff);
            for (;;) {
                #pragma unroll
                for (int kb = 0; kb < 32; ++kb) {
                    A[kb].q[0] = coh_load8(hq + kb * 8);
                    A[kb].q[1] = coh_load8(hq + kb * 8 + 1);
                }
                bool ok = true;
                #pragma unroll
                for (int kb = 0; kb < 32; ++kb)
                    ok = ok && (A[kb].q[0] != SENT64) && (A[kb].q[1] != SENT64);
                if (__all(ok)) break;
                __builtin_amdgcn_s_sleep(1);   // bounded backoff on miss
            }
        }
        __builtin_amdgcn_sched_barrier(0);

        // G[64 x 32] += h_t @ Whh_slice^T (K = 1024)
        #pragma unroll
        for (int kb = 0; kb < 32; kb += 2) {
            bf16x8 b0a = *(const bf16x8*)(&sWhh[l15][kb * 32 + koff]);
            bf16x8 b1a = *(const bf16x8*)(&sWhh[16 + l15][kb * 32 + koff]);
            bf16x8 b0b = *(const bf16x8*)(&sWhh[l15][(kb + 1) * 32 + koff]);
            bf16x8 b1b = *(const bf16x8*)(&sWhh[16 + l15][(kb + 1) * 32 + koff]);
            acc0e = __builtin_amdgcn_mfma_f32_16x16x32_bf16(A[kb].v,     b0a, acc0e, 0, 0, 0);
            acc1e = __builtin_amdgcn_mfma_f32_16x16x32_bf16(A[kb].v,     b1a, acc1e, 0, 0, 0);
            acc0o = __builtin_amdgcn_mfma_f32_16x16x32_bf16(A[kb + 1].v, b0b, acc0o, 0, 0, 0);
            acc1o = __builtin_amdgcn_mfma_f32_16x16x32_bf16(A[kb + 1].v, b1b, acc1o, 0, 0, 0);
        }
        f32x4 acc0 = acc0e + acc0o;
        f32x4 acc1 = acc1e + acc1o;
        #pragma unroll
        for (int r = 0; r < 4; ++r) {
            sG[wave * 16 + quad * 4 + r][l15]      = acc0[r];
            sG[wave * 16 + quad * 4 + r][16 + l15] = acc1[r];
        }
        __syncthreads();

        // elementwise gate math; pack h slice into LDS
        #pragma unroll
        for (int p = tid; p < B * 8; p += 256) {
            int b = p >> 3, j = p & 7;
            float gi = sG[b][j]      + sBias[j];
            float gf = sG[b][8 + j]  + sBias[8 + j];
            float gg = sG[b][16 + j] + sBias[16 + j];
            float go = sG[b][24 + j] + sBias[24 + j];
            float i_ = 1.f / (1.f + __expf(-gi));
            float f_ = 1.f / (1.f + __expf(-gf));
            float g_ = fast_tanh(gg);
            float o_ = 1.f / (1.f + __expf(-go));
            float c  = f_ * sC[b][j] + i_ * g_;
            sC[b][j] = c;
            ((unsigned short*)&sH[b])[j] = f2bf(o_ * fast_tanh(c));
        }
        __syncthreads();

        // publish: fire-and-forget sc1 stores. NO drain, NO flag — consumers
        // validate the data itself. Values are in registers before the stores,
        // so next-step sH rewrites can't race them.
        if (tid < 64) {
            const unsigned long long* src = (const unsigned long long*)&sH[tid];
            unsigned long long v0 = src[0], v1 = src[1];
            unsigned long long* dst = (unsigned long long*)
                (hbuf + ((size_t)(dec * (T + 1) + t + 1) * B + tid) * H + u0);
            coh_store8(dst, v0);
            coh_store8(dst + 1, v1);
        }
    }

    // completion flag once: drain ALL publish stores, then announce done.
    if (tid < 64) {
        asm volatile("s_waitcnt vmcnt(0)" ::: "memory");
        if (lane == 0) {
            __hip_atomic_store(myflag, (unsigned)T, __ATOMIC_RELAXED,
                               __HIP_MEMORY_SCOPE_AGENT);
        }
    }

    // wait for BOTH decoders to finish everything (output tiles span both)
    {
        if (wave == 0) {
            const unsigned needT = (unsigned)T;
            const unsigned long long* aw = (const unsigned long long*)flags;
            for (;;) {
                unsigned long long w0 = __hip_atomic_load(&aw[lane],      __ATOMIC_RELAXED, __HIP_MEMORY_SCOPE_AGENT);
                unsigned long long w1 = __hip_atomic_load(&aw[64 + lane], __ATOMIC_RELAXED, __HIP_MEMORY_SCOPE_AGENT);
                bool ok = ((unsigned)w0 >= needT) && ((unsigned)(w0 >> 32) >= needT) &&
                          ((unsigned)w1 >= needT) && ((unsigned)(w1 >> 32) >= needT);
                if (__all(ok)) break;
                __builtin_amdgcn_s_sleep(1);
            }
            __builtin_amdgcn_fence(__ATOMIC_ACQUIRE, "agent");   // invalidate before plain reads
        }
        __syncthreads();
    }

    // ---- output projection: Y[dec][t] = h @ W_out^T + b_out ----
    for (int qq = 0; qq < 4; ++qq) {
        int q    = bid * 4 + qq;          // 0 .. 1023
        int ydec = q >> 9;
        int yt   = q & 511;
        const float* bout = ydec ? bbout : fbout;
        const unsigned short* hr = hbuf + ((size_t)(ydec * (T + 1) + yt + 1) * B + m) * H;
        const unsigned short* wb = woutbf + (size_t)ydec * D * H;

        // hoist + cluster the h-row fragments: loaded once, reused for 5 nt tiles
        bf16x8 Ah[32];
        #pragma unroll
        for (int kb = 0; kb < 32; ++kb)
            Ah[kb] = *(const bf16x8*)(hr + kb * 32 + koff);
        __builtin_amdgcn_sched_barrier(0);

        #pragma unroll
        for (int nt = 0; nt < 5; ++nt) {
            f32x4 acc = {0.f, 0.f, 0.f, 0.f};
            const unsigned short* wrow = wb + (size_t)(nt * 16 + l15) * H;
            #pragma unroll 8
            for (int kb = 0; kb < H / 32; ++kb) {
                bf16x8 bf = *(const bf16x8*)(wrow + kb * 32 + koff);
                acc = __builtin_amdgcn_mfma_f32_16x16x32_bf16(Ah[kb], bf, acc, 0, 0, 0);
            }
            float bo = bout[nt * 16 + l15];
            #pragma unroll
            for (int r = 0; r < 4; ++r) {
                int bb_ = wave * 16 + quad * 4 + r;
                out[((size_t)(ydec * T + yt) * B + bb_) * D + nt * 16 + l15] = acc[r] + bo;
            }
        }
    }
}

extern "C" void kernel_launch(void* const* d_in, const int* in_sizes, int n_in,
                              void* d_out, int out_size, void* d_ws, size_t ws_size,
                              hipStream_t stream)
{
    const float* input  = (const float*)d_in[0];
    const float* target = (const float*)d_in[1];
    const float* Win    = (const float*)d_in[2];
    const float* bin    = (const float*)d_in[3];
    const float* fWih   = (const float*)d_in[4];
    const float* fWhh   = (const float*)d_in[5];
    const float* fb     = (const float*)d_in[6];
    const float* fWout  = (const float*)d_in[7];
    const float* fbout  = (const float*)d_in[8];
    const float* bWih   = (const float*)d_in[9];
    const float* bWhh   = (const float*)d_in[10];
    const float* bb     = (const float*)d_in[11];
    const float* bWout  = (const float*)d_in[12];
    const float* bbout  = (const float*)d_in[13];
    float* out = (float*)d_out;

    unsigned short* hbuf  = (unsigned short*)d_ws;
    unsigned short* xsb   = (unsigned short*)((char*)d_ws + HBUF_BYTES);
    unsigned short* wout  = (unsigned short*)((char*)d_ws + HBUF_BYTES + XS_BYTES);
    unsigned int*   flags = (unsigned int*)((char*)d_ws + HBUF_BYTES + XS_BYTES + WOUT_BYTES);

    prep_x0<<<B * D, 64, 0, stream>>>(input, Win, bin, xsb);
    prep_xs<<<(T * B * DP + 255) / 256, 256, 0, stream>>>(target, xsb);
    prep_sent<<<4096, 256, 0, stream>>>((u32x4*)hbuf);
    {
        int n = 2 * D * H + 2 * B * H + NFLAG;
        prep_misc<<<(n + 255) / 256, 256, 0, stream>>>(fWout, bWout, wout, hbuf, flags);
    }

    void* args[] = { &hbuf, &xsb, &wout, &flags,
                     (void*)&fWih, (void*)&fWhh, (void*)&fb,
                     (void*)&bWih, (void*)&bWhh, (void*)&bb,
                     (void*)&fbout, (void*)&bbout, &out };
    hipLaunchCooperativeKernel((void*)lstm_main, dim3(256), dim3(256), args, 0, stream);
}

// Round 10
// 6133.192 us; speedup vs baseline: 1.1536x; 1.1536x over previous
//
#include <hip/hip_runtime.h>
#include <hip/hip_bf16.h>
#include <cstdint>
#include <cstddef>

#define H   1024
#define D   80
#define DP  96          // D padded to multiple of 32 (zero-padded)
#define T   512
#define B   64
#define NG  32          // gate rows per block (4 gates x 8 hidden units)
#define KP  1032        // LDS row stride for Whh slice (+8 bf16 pad)
#define KPI 104         // LDS row stride for Wih slice

typedef __attribute__((ext_vector_type(8))) short bf16x8;   // 8 bf16 (MFMA A/B frag)
typedef __attribute__((ext_vector_type(4))) float f32x4;    // MFMA C/D frag
typedef __attribute__((ext_vector_type(4))) unsigned int u32x4;

// bf16 +inf replicated: h = o*tanh(c) in [-1,1] can NEVER produce this pattern.
#define SENT64 0x7F807F807F807F80ull

// ws layout
#define HBUF_ELEMS ((size_t)2 * (T + 1) * B * H)            // bf16 h history, slot 0 = h_{-1}=0
#define HBUF_BYTES (HBUF_ELEMS * 2)
#define XS_ELEMS   ((size_t)T * B * DP)                     // bf16 teacher-forced inputs (padded)
#define XS_BYTES   (XS_ELEMS * 2)
#define WOUT_ELEMS ((size_t)2 * D * H)                      // bf16 W_out both decoders
#define WOUT_BYTES (WOUT_ELEMS * 2)
#define NFLAG      256                                       // completion flags (final barrier only)

__device__ __forceinline__ unsigned short f2bf(float x) {
    unsigned int u = __float_as_uint(x);
    unsigned int r = (u + 0x7FFFu + ((u >> 16) & 1u)) >> 16;   // RNE
    return (unsigned short)r;
}

// overflow-safe fast tanh: 2*sigmoid(2x)-1 (validated rounds 5-9, absmax unchanged)
__device__ __forceinline__ float fast_tanh(float x) {
    return 2.f / (1.f + __expf(-2.f * x)) - 1.f;
}

// agent-scope (coherence-point) 8-byte store: sc1 path, bypasses L1/L2 write-back.
__device__ __forceinline__ void coh_store8(unsigned long long* p, unsigned long long v) {
    __hip_atomic_store(p, v, __ATOMIC_RELAXED, __HIP_MEMORY_SCOPE_AGENT);
}

// ---- prep: x0 = input[T-1] @ W_in^T + b_in ----
__global__ void prep_x0(const float* __restrict__ inp, const float* __restrict__ Win,
                        const float* __restrict__ bin, unsigned short* __restrict__ xs)
{
    int o = blockIdx.x;                // 0 .. B*D-1
    int b = o / D, d = o % D;
    int lane = threadIdx.x;
    const float* irow = inp + ((size_t)(T - 1) * B + b) * H;
    const float* wrow = Win + (size_t)d * H;
    float s = 0.f;
    for (int k = lane; k < H; k += 64) s += irow[k] * wrow[k];
    for (int off = 32; off > 0; off >>= 1) s += __shfl_down(s, off, 64);
    if (lane == 0) xs[b * DP + d] = f2bf(s + bin[d]);
}

// ---- prep: xs[t] = target[t-1] (t>=1), zero pads ----
__global__ void prep_xs(const float* __restrict__ tgt, unsigned short* __restrict__ xs)
{
    int idx = blockIdx.x * 256 + threadIdx.x;
    if (idx >= T * B * DP) return;
    int t = idx / (B * DP);
    int r = idx % (B * DP);
    int b = r / DP, d = r % DP;
    if (d >= D) { xs[idx] = 0; return; }
    if (t == 0) return;
    xs[idx] = f2bf(tgt[((size_t)(t - 1) * B + b) * D + d]);
}

// ---- prep: fill hbuf slots 1..T (both decoders) with the sentinel pattern.
// Plain stores; dispatch-boundary writeback makes them globally visible before
// lstm_main starts (same mechanism all prep->main data already relies on).
__global__ void prep_sent(u32x4* __restrict__ hbuf16)
{
    const size_t perdec = (size_t)T * B * H / 8;        // 16B chunks per decoder
    const u32x4 s4 = {0x7F807F80u, 0x7F807F80u, 0x7F807F80u, 0x7F807F80u};
    for (size_t p = (size_t)blockIdx.x * 256 + threadIdx.x;
         p < 2 * perdec; p += (size_t)gridDim.x * 256) {
        size_t dec = p / perdec, r = p % perdec;
        hbuf16[(dec * (T + 1) + 1) * (B * H / 8) + r] = s4;
    }
}

// ---- prep: W_out->bf16, zero h slot 0, zero flags ----
__global__ void prep_misc(const float* __restrict__ fWout, const float* __restrict__ bWout,
                          unsigned short* __restrict__ woutbf, unsigned short* __restrict__ hbuf,
                          unsigned int* __restrict__ flags)
{
    int idx = blockIdx.x * 256 + threadIdx.x;
    const int NW = 2 * D * H;
    const int NZ = 2 * B * H;
    if (idx < NW) {
        int dec = idx / (D * H); int rr = idx % (D * H);
        woutbf[idx] = f2bf((dec ? bWout : fWout)[rr]);
    } else if (idx < NW + NZ) {
        int z = idx - NW;
        int dec = z / (B * H); int rr = z % (B * H);
        hbuf[(size_t)dec * (T + 1) * B * H + rr] = 0;
    } else if (idx < NW + NZ + NFLAG) {
        flags[idx - NW - NZ] = 0;
    }
}

// ---- main persistent kernel: 256 blocks x 256 threads (1 block/CU) ----
// Sync design: sentinel-validated data. Producers fire sc1 stores and move on
// (no drain, no flag). Consumers read h with PLAIN clustered b128 loads (fast,
// R8-proven) and validate each 8B granule against the sentinel; only on a miss
// do they pay an acquire fence (L1/L2 invalidate) and retry from the MALL.
__global__ void __launch_bounds__(256, 1)
lstm_main(unsigned short* __restrict__ hbuf,
          const unsigned short* __restrict__ xs,
          const unsigned short* __restrict__ woutbf,
          unsigned int* __restrict__ flags,
          const float* __restrict__ fWih, const float* __restrict__ fWhh, const float* __restrict__ fbias,
          const float* __restrict__ bWih, const float* __restrict__ bWhh, const float* __restrict__ bbias,
          const float* __restrict__ fbout, const float* __restrict__ bbout,
          float* __restrict__ out)
{
    const int bid  = blockIdx.x;
    const int dec  = bid >> 7;          // 0 = fwd, 1 = bwd
    const int blk  = bid & 127;
    const int u0   = blk << 3;          // first of 8 owned hidden units
    const int tid  = threadIdx.x;
    const int wave = tid >> 6;
    const int lane = tid & 63;
    const int l15  = lane & 15;
    const int quad = lane >> 4;
    const int koff = quad * 8;

    __shared__ unsigned short sWhh[NG][KP];    // 66 KB
    __shared__ unsigned short sWih[NG][KPI];   // 6.5 KB
    __shared__ float sBias[NG];
    __shared__ float sG[B][33];
    __shared__ float sC[B][8];
    __shared__ bf16x8 sH[B];                   // packed h slice for vector publish

    const float* Wih  = dec ? bWih  : fWih;
    const float* Whh  = dec ? bWhh  : fWhh;
    const float* bias = dec ? bbias : fbias;

    for (int e = tid; e < NG * H; e += 256) {
        int n = e >> 10, k = e & (H - 1);
        int row = (n >> 3) * H + u0 + (n & 7);
        sWhh[n][k] = f2bf(Whh[(size_t)row * H + k]);
    }
    for (int e = tid; e < NG * KPI; e += 256) {
        int n = e / KPI, dd = e % KPI;
        int row = (n >> 3) * H + u0 + (n & 7);
        sWih[n][dd] = (dd < D) ? f2bf(Wih[(size_t)row * D + dd]) : 0;
    }
    if (tid < NG) {
        int row = (tid >> 3) * H + u0 + (tid & 7);
        sBias[tid] = bias[row];
    }
    for (int e = tid; e < B * 8; e += 256) sC[e >> 3][e & 7] = 0.f;
    __syncthreads();

    const int m = wave * 16 + l15;   // batch row this lane loads for A-frags
    unsigned int* myflag = flags + bid;

    union FragU { unsigned long long q[2]; bf16x8 v; };

    for (int t = 0; t < T; ++t) {
        // 4 accumulator chains: even/odd k x (units 0-7 / 8-15 columns)
        f32x4 acc0e = {0.f,0.f,0.f,0.f}, acc0o = {0.f,0.f,0.f,0.f};
        f32x4 acc1e = {0.f,0.f,0.f,0.f}, acc1o = {0.f,0.f,0.f,0.f};

        // x_t @ Wih^T first — independent of h_t, overlaps producer store flight
        const unsigned short* xrow = xs + ((size_t)t * B + m) * DP;
        #pragma unroll
        for (int kb = 0; kb < DP / 32; ++kb) {
            bf16x8 a  = *(const bf16x8*)(xrow + kb * 32 + koff);
            bf16x8 b0 = *(const bf16x8*)(&sWih[l15][kb * 32 + koff]);
            bf16x8 b1 = *(const bf16x8*)(&sWih[16 + l15][kb * 32 + koff]);
            acc0e = __builtin_amdgcn_mfma_f32_16x16x32_bf16(a, b0, acc0e, 0, 0, 0);
            acc1e = __builtin_amdgcn_mfma_f32_16x16x32_bf16(a, b1, acc1e, 0, 0, 0);
        }

        // SENTINEL-VALIDATED h read: clustered PLAIN b128 loads (R8 speed).
        // Each 8B granule is exactly one producer 8B sc1 store (4 units), so a
        // granule is either all-sentinel or all-real — no tearing. Retry path
        // pays an agent acquire fence (invalidates L1/L2 -> next read reaches
        // the MALL; no stale-sentinel livelock). t=0 reads the zeroed slot.
        FragU A[32];
        {
            const unsigned short* hrow =
                hbuf + ((size_t)(dec * (T + 1) + t) * B + m) * H + koff;
            for (;;) {
                #pragma unroll
                for (int kb = 0; kb < 32; ++kb)
                    A[kb].v = *(const bf16x8*)(hrow + kb * 32);
                bool ok = true;
                #pragma unroll
                for (int kb = 0; kb < 32; ++kb)
                    ok = ok && (A[kb].q[0] != SENT64) && (A[kb].q[1] != SENT64);
                if (__all(ok)) break;
                __builtin_amdgcn_fence(__ATOMIC_ACQUIRE, "agent");  // slow path only
            }
        }
        __builtin_amdgcn_sched_barrier(0);

        // G[64 x 32] += h_t @ Whh_slice^T (K = 1024)
        #pragma unroll
        for (int kb = 0; kb < 32; kb += 2) {
            bf16x8 b0a = *(const bf16x8*)(&sWhh[l15][kb * 32 + koff]);
            bf16x8 b1a = *(const bf16x8*)(&sWhh[16 + l15][kb * 32 + koff]);
            bf16x8 b0b = *(const bf16x8*)(&sWhh[l15][(kb + 1) * 32 + koff]);
            bf16x8 b1b = *(const bf16x8*)(&sWhh[16 + l15][(kb + 1) * 32 + koff]);
            acc0e = __builtin_amdgcn_mfma_f32_16x16x32_bf16(A[kb].v,     b0a, acc0e, 0, 0, 0);
            acc1e = __builtin_amdgcn_mfma_f32_16x16x32_bf16(A[kb].v,     b1a, acc1e, 0, 0, 0);
            acc0o = __builtin_amdgcn_mfma_f32_16x16x32_bf16(A[kb + 1].v, b0b, acc0o, 0, 0, 0);
            acc1o = __builtin_amdgcn_mfma_f32_16x16x32_bf16(A[kb + 1].v, b1b, acc1o, 0, 0, 0);
        }
        f32x4 acc0 = acc0e + acc0o;
        f32x4 acc1 = acc1e + acc1o;
        #pragma unroll
        for (int r = 0; r < 4; ++r) {
            sG[wave * 16 + quad * 4 + r][l15]      = acc0[r];
            sG[wave * 16 + quad * 4 + r][16 + l15] = acc1[r];
        }
        __syncthreads();

        // elementwise gate math; pack h slice into LDS
        #pragma unroll
        for (int p = tid; p < B * 8; p += 256) {
            int b = p >> 3, j = p & 7;
            float gi = sG[b][j]      + sBias[j];
            float gf = sG[b][8 + j]  + sBias[8 + j];
            float gg = sG[b][16 + j] + sBias[16 + j];
            float go = sG[b][24 + j] + sBias[24 + j];
            float i_ = 1.f / (1.f + __expf(-gi));
            float f_ = 1.f / (1.f + __expf(-gf));
            float g_ = fast_tanh(gg);
            float o_ = 1.f / (1.f + __expf(-go));
            float c  = f_ * sC[b][j] + i_ * g_;
            sC[b][j] = c;
            ((unsigned short*)&sH[b])[j] = f2bf(o_ * fast_tanh(c));
        }
        __syncthreads();

        // publish: fire-and-forget sc1 stores spread over 128 threads (2 waves).
        // No drain, no flag — consumers validate the data itself. The stores
        // get drained by the NEXT step's __syncthreads vmcnt(0), off the
        // critical sync path.
        if (tid < 128) {
            int b = tid >> 1, hf = tid & 1;
            unsigned long long v = ((const unsigned long long*)&sH[b])[hf];
            unsigned long long* dst = (unsigned long long*)
                (hbuf + ((size_t)(dec * (T + 1) + t + 1) * B + b) * H + u0);
            coh_store8(dst + hf, v);
        }
    }

    // completion: drain own publish stores, then one flag per block.
    asm volatile("s_waitcnt vmcnt(0)" ::: "memory");
    __syncthreads();
    if (tid == 0) {
        __hip_atomic_store(myflag, (unsigned)T, __ATOMIC_RELAXED,
                           __HIP_MEMORY_SCOPE_AGENT);
    }

    // wait for BOTH decoders to finish everything (output tiles span both)
    {
        if (wave == 0) {
            const unsigned needT = (unsigned)T;
            const unsigned long long* aw = (const unsigned long long*)flags;
            for (;;) {
                unsigned long long w0 = __hip_atomic_load(&aw[lane],      __ATOMIC_RELAXED, __HIP_MEMORY_SCOPE_AGENT);
                unsigned long long w1 = __hip_atomic_load(&aw[64 + lane], __ATOMIC_RELAXED, __HIP_MEMORY_SCOPE_AGENT);
                bool ok = ((unsigned)w0 >= needT) && ((unsigned)(w0 >> 32) >= needT) &&
                          ((unsigned)w1 >= needT) && ((unsigned)(w1 >> 32) >= needT);
                if (__all(ok)) break;
                __builtin_amdgcn_s_sleep(1);
            }
            __builtin_amdgcn_fence(__ATOMIC_ACQUIRE, "agent");   // invalidate before plain reads
        }
        __syncthreads();
    }

    // ---- output projection: Y[dec][t] = h @ W_out^T + b_out ----
    for (int qq = 0; qq < 4; ++qq) {
        int q    = bid * 4 + qq;          // 0 .. 1023
        int ydec = q >> 9;
        int yt   = q & 511;
        const float* bout = ydec ? bbout : fbout;
        const unsigned short* hr = hbuf + ((size_t)(ydec * (T + 1) + yt + 1) * B + m) * H;
        const unsigned short* wb = woutbf + (size_t)ydec * D * H;

        // hoist + cluster the h-row fragments: loaded once, reused for 5 nt tiles
        bf16x8 Ah[32];
        #pragma unroll
        for (int kb = 0; kb < 32; ++kb)
            Ah[kb] = *(const bf16x8*)(hr + kb * 32 + koff);
        __builtin_amdgcn_sched_barrier(0);

        #pragma unroll
        for (int nt = 0; nt < 5; ++nt) {
            f32x4 acc = {0.f, 0.f, 0.f, 0.f};
            const unsigned short* wrow = wb + (size_t)(nt * 16 + l15) * H;
            #pragma unroll 8
            for (int kb = 0; kb < H / 32; ++kb) {
                bf16x8 bf = *(const bf16x8*)(wrow + kb * 32 + koff);
                acc = __builtin_amdgcn_mfma_f32_16x16x32_bf16(Ah[kb], bf, acc, 0, 0, 0);
            }
            float bo = bout[nt * 16 + l15];
            #pragma unroll
            for (int r = 0; r < 4; ++r) {
                int bb_ = wave * 16 + quad * 4 + r;
                out[((size_t)(ydec * T + yt) * B + bb_) * D + nt * 16 + l15] = acc[r] + bo;
            }
        }
    }
}

extern "C" void kernel_launch(void* const* d_in, const int* in_sizes, int n_in,
                              void* d_out, int out_size, void* d_ws, size_t ws_size,
                              hipStream_t stream)
{
    const float* input  = (const float*)d_in[0];
    const float* target = (const float*)d_in[1];
    const float* Win    = (const float*)d_in[2];
    const float* bin    = (const float*)d_in[3];
    const float* fWih   = (const float*)d_in[4];
    const float* fWhh   = (const float*)d_in[5];
    const float* fb     = (const float*)d_in[6];
    const float* fWout  = (const float*)d_in[7];
    const float* fbout  = (const float*)d_in[8];
    const float* bWih   = (const float*)d_in[9];
    const float* bWhh   = (const float*)d_in[10];
    const float* bb     = (const float*)d_in[11];
    const float* bWout  = (const float*)d_in[12];
    const float* bbout  = (const float*)d_in[13];
    float* out = (float*)d_out;

    unsigned short* hbuf  = (unsigned short*)d_ws;
    unsigned short* xsb   = (unsigned short*)((char*)d_ws + HBUF_BYTES);
    unsigned short* wout  = (unsigned short*)((char*)d_ws + HBUF_BYTES + XS_BYTES);
    unsigned int*   flags = (unsigned int*)((char*)d_ws + HBUF_BYTES + XS_BYTES + WOUT_BYTES);

    prep_x0<<<B * D, 64, 0, stream>>>(input, Win, bin, xsb);
    prep_xs<<<(T * B * DP + 255) / 256, 256, 0, stream>>>(target, xsb);
    prep_sent<<<4096, 256, 0, stream>>>((u32x4*)hbuf);
    {
        int n = 2 * D * H + 2 * B * H + NFLAG;
        prep_misc<<<(n + 255) / 256, 256, 0, stream>>>(fWout, bWout, wout, hbuf, flags);
    }

    void* args[] = { &hbuf, &xsb, &wout, &flags,
                     (void*)&fWih, (void*)&fWhh, (void*)&fb,
                     (void*)&bWih, (void*)&bWhh, (void*)&bb,
                     (void*)&fbout, (void*)&bbout, &out };
    hipLaunchCooperativeKernel((void*)lstm_main, dim3(256), dim3(256), args, 0, stream);
}

// Round 11
// 3886.354 us; speedup vs baseline: 1.8205x; 1.5781x over previous
//
#include <hip/hip_runtime.h>
#include <hip/hip_bf16.h>
#include <cstdint>
#include <cstddef>

#define H   1024
#define D   80
#define DP  96          // D padded to multiple of 32 (zero-padded)
#define T   512
#define B   64
#define NG  32          // gate rows per block (4 gates x 8 hidden units)
#define KP  1032        // LDS row stride for Whh slice (+8 bf16 pad)
#define KPI 104         // LDS row stride for Wih slice

typedef __attribute__((ext_vector_type(8))) short bf16x8;   // 8 bf16 (MFMA A/B frag)
typedef __attribute__((ext_vector_type(4))) float f32x4;    // MFMA C/D frag

// ws layout
#define HBUF_ELEMS ((size_t)2 * (T + 1) * B * H)            // bf16 h history, slot 0 = h_{-1}=0
#define HBUF_BYTES (HBUF_ELEMS * 2)
#define XS_ELEMS   ((size_t)T * B * DP)                     // bf16 teacher-forced inputs (padded)
#define XS_BYTES   (XS_ELEMS * 2)
#define WOUT_ELEMS ((size_t)2 * D * H)                      // bf16 W_out both decoders
#define WOUT_BYTES (WOUT_ELEMS * 2)
#define NFLAG      256                                       // flags[bid], 4B each (8B-aligned base)

__device__ __forceinline__ unsigned short f2bf(float x) {
    unsigned int u = __float_as_uint(x);
    unsigned int r = (u + 0x7FFFu + ((u >> 16) & 1u)) >> 16;   // RNE
    return (unsigned short)r;
}

// overflow-safe fast tanh: 2*sigmoid(2x)-1 (validated rounds 5-10, absmax unchanged)
__device__ __forceinline__ float fast_tanh(float x) {
    return 2.f / (1.f + __expf(-2.f * x)) - 1.f;
}

// agent-scope (coherence-point) 8-byte store: sc1 path, bypasses L1/L2 write-back.
__device__ __forceinline__ void coh_store8(unsigned long long* p, unsigned long long v) {
    __hip_atomic_store(p, v, __ATOMIC_RELAXED, __HIP_MEMORY_SCOPE_AGENT);
}

// ---- prep: x0 = input[T-1] @ W_in^T + b_in ----
__global__ void prep_x0(const float* __restrict__ inp, const float* __restrict__ Win,
                        const float* __restrict__ bin, unsigned short* __restrict__ xs)
{
    int o = blockIdx.x;                // 0 .. B*D-1
    int b = o / D, d = o % D;
    int lane = threadIdx.x;
    const float* irow = inp + ((size_t)(T - 1) * B + b) * H;
    const float* wrow = Win + (size_t)d * H;
    float s = 0.f;
    for (int k = lane; k < H; k += 64) s += irow[k] * wrow[k];
    for (int off = 32; off > 0; off >>= 1) s += __shfl_down(s, off, 64);
    if (lane == 0) xs[b * DP + d] = f2bf(s + bin[d]);
}

// ---- prep: xs[t] = target[t-1] (t>=1), zero pads ----
__global__ void prep_xs(const float* __restrict__ tgt, unsigned short* __restrict__ xs)
{
    int idx = blockIdx.x * 256 + threadIdx.x;
    if (idx >= T * B * DP) return;
    int t = idx / (B * DP);
    int r = idx % (B * DP);
    int b = r / DP, d = r % DP;
    if (d >= D) { xs[idx] = 0; return; }
    if (t == 0) return;
    xs[idx] = f2bf(tgt[((size_t)(t - 1) * B + b) * D + d]);
}

// ---- prep: W_out->bf16, zero h slot 0, zero flags ----
__global__ void prep_misc(const float* __restrict__ fWout, const float* __restrict__ bWout,
                          unsigned short* __restrict__ woutbf, unsigned short* __restrict__ hbuf,
                          unsigned int* __restrict__ flags)
{
    int idx = blockIdx.x * 256 + threadIdx.x;
    const int NW = 2 * D * H;
    const int NZ = 2 * B * H;
    if (idx < NW) {
        int dec = idx / (D * H); int rr = idx % (D * H);
        woutbf[idx] = f2bf((dec ? bWout : fWout)[rr]);
    } else if (idx < NW + NZ) {
        int z = idx - NW;
        int dec = z / (B * H); int rr = z % (B * H);
        hbuf[(size_t)dec * (T + 1) * B * H + rr] = 0;
    } else if (idx < NW + NZ + NFLAG) {
        flags[idx - NW - NZ] = 0;
    }
}

// ---- main persistent kernel: 256 blocks x 256 threads (1 block/CU) ----
// amdgpu_waves_per_eu(1,1): pin occupancy target to 1 wave/EU so the register
// allocator uses the full 512-VGPR budget instead of spilling the A[32]
// cluster to scratch (R8 evidence: VGPR_Count=132 < 175 demand, WRITE_SIZE
// +131 MB of scratch traffic, ~12 serialized ~200cy reloads in the MFMA chain).
__global__ void __launch_bounds__(256, 1) __attribute__((amdgpu_waves_per_eu(1, 1)))
lstm_main(unsigned short* __restrict__ hbuf,
          const unsigned short* __restrict__ xs,
          const unsigned short* __restrict__ woutbf,
          unsigned int* __restrict__ flags,
          const float* __restrict__ fWih, const float* __restrict__ fWhh, const float* __restrict__ fbias,
          const float* __restrict__ bWih, const float* __restrict__ bWhh, const float* __restrict__ bbias,
          const float* __restrict__ fbout, const float* __restrict__ bbout,
          float* __restrict__ out)
{
    const int bid  = blockIdx.x;
    const int dec  = bid >> 7;          // 0 = fwd, 1 = bwd
    const int blk  = bid & 127;
    const int u0   = blk << 3;          // first of 8 owned hidden units
    const int tid  = threadIdx.x;
    const int wave = tid >> 6;
    const int lane = tid & 63;
    const int l15  = lane & 15;
    const int quad = lane >> 4;
    const int koff = quad * 8;

    __shared__ unsigned short sWhh[NG][KP];    // 66 KB
    __shared__ unsigned short sWih[NG][KPI];   // 6.5 KB
    __shared__ float sBias[NG];
    __shared__ float sG[B][33];
    __shared__ float sC[B][8];
    __shared__ bf16x8 sH[B];                   // packed h slice for vector publish

    const float* Wih  = dec ? bWih  : fWih;
    const float* Whh  = dec ? bWhh  : fWhh;
    const float* bias = dec ? bbias : fbias;

    for (int e = tid; e < NG * H; e += 256) {
        int n = e >> 10, k = e & (H - 1);
        int row = (n >> 3) * H + u0 + (n & 7);
        sWhh[n][k] = f2bf(Whh[(size_t)row * H + k]);
    }
    for (int e = tid; e < NG * KPI; e += 256) {
        int n = e / KPI, dd = e % KPI;
        int row = (n >> 3) * H + u0 + (n & 7);
        sWih[n][dd] = (dd < D) ? f2bf(Wih[(size_t)row * D + dd]) : 0;
    }
    if (tid < NG) {
        int row = (tid >> 3) * H + u0 + (tid & 7);
        sBias[tid] = bias[row];
    }
    for (int e = tid; e < B * 8; e += 256) sC[e >> 3][e & 7] = 0.f;
    __syncthreads();

    const int m = wave * 16 + l15;   // batch row this lane loads for A-frags
    unsigned int* myflag = flags + bid;
    // packed poll: lane i reads ONE u64 covering producer flags (2i, 2i+1)
    const unsigned long long* pw = (const unsigned long long*)(flags + dec * 128);

    for (int t = 0; t < T; ++t) {
        // 4 accumulator chains: even/odd k x (units 0-7 / 8-15 columns)
        f32x4 acc0e = {0.f,0.f,0.f,0.f}, acc0o = {0.f,0.f,0.f,0.f};
        f32x4 acc1e = {0.f,0.f,0.f,0.f}, acc1o = {0.f,0.f,0.f,0.f};

        // x_t @ Wih^T first — independent of h_t, hides in the wait window
        const unsigned short* xrow = xs + ((size_t)t * B + m) * DP;
        #pragma unroll
        for (int kb = 0; kb < DP / 32; ++kb) {
            bf16x8 a  = *(const bf16x8*)(xrow + kb * 32 + koff);
            bf16x8 b0 = *(const bf16x8*)(&sWih[l15][kb * 32 + koff]);
            bf16x8 b1 = *(const bf16x8*)(&sWih[16 + l15][kb * 32 + koff]);
            acc0e = __builtin_amdgcn_mfma_f32_16x16x32_bf16(a, b0, acc0e, 0, 0, 0);
            acc1e = __builtin_amdgcn_mfma_f32_16x16x32_bf16(a, b1, acc1e, 0, 0, 0);
        }

        // EVERY wave polls the 128 producer flags independently (64 u64 words,
        // 1 load/lane/iter, pure spin) and proceeds without a block barrier —
        // each wave's h rows are private; all LDS hazards are covered by the
        // sG-sync and post-gate sync below. Ordering: producers drain h stores
        // to the coherence point before the flag store; write-once hbuf slots
        // -> no stale cached lines (proven pattern, rounds 1-8).
        if (t > 0) {
            const unsigned need = (unsigned)t;
            for (;;) {
                unsigned long long w = __hip_atomic_load(&pw[lane], __ATOMIC_RELAXED,
                                                         __HIP_MEMORY_SCOPE_AGENT);
                unsigned lo = (unsigned)w, hi = (unsigned)(w >> 32);
                if (__all((lo >= need) && (hi >= need))) break;
            }
        }

        // G[64 x 32] += h_t @ Whh_slice^T (K = 1024).
        // CLUSTERED LOADS: all 32 h-fragment loads back-to-back (one round trip
        // + L2-BW streaming), schedule pinned with sched_barrier(0). With the
        // waves_per_eu(1,1) budget the frags stay in registers (no scratch).
        {
            const unsigned short* hrow =
                hbuf + ((size_t)(dec * (T + 1) + t) * B + m) * H + koff;
            bf16x8 A[32];
            #pragma unroll
            for (int kb = 0; kb < 32; ++kb)
                A[kb] = *(const bf16x8*)(hrow + kb * 32);
            __builtin_amdgcn_sched_barrier(0);
            #pragma unroll
            for (int kb = 0; kb < 32; kb += 2) {
                bf16x8 b0a = *(const bf16x8*)(&sWhh[l15][kb * 32 + koff]);
                bf16x8 b1a = *(const bf16x8*)(&sWhh[16 + l15][kb * 32 + koff]);
                bf16x8 b0b = *(const bf16x8*)(&sWhh[l15][(kb + 1) * 32 + koff]);
                bf16x8 b1b = *(const bf16x8*)(&sWhh[16 + l15][(kb + 1) * 32 + koff]);
                acc0e = __builtin_amdgcn_mfma_f32_16x16x32_bf16(A[kb],     b0a, acc0e, 0, 0, 0);
                acc1e = __builtin_amdgcn_mfma_f32_16x16x32_bf16(A[kb],     b1a, acc1e, 0, 0, 0);
                acc0o = __builtin_amdgcn_mfma_f32_16x16x32_bf16(A[kb + 1], b0b, acc0o, 0, 0, 0);
                acc1o = __builtin_amdgcn_mfma_f32_16x16x32_bf16(A[kb + 1], b1b, acc1o, 0, 0, 0);
            }
        }
        f32x4 acc0 = acc0e + acc0o;
        f32x4 acc1 = acc1e + acc1o;
        #pragma unroll
        for (int r = 0; r < 4; ++r) {
            sG[wave * 16 + quad * 4 + r][l15]      = acc0[r];
            sG[wave * 16 + quad * 4 + r][16 + l15] = acc1[r];
        }
        __syncthreads();

        // elementwise gate math; pack h slice into LDS
        #pragma unroll
        for (int p = tid; p < B * 8; p += 256) {
            int b = p >> 3, j = p & 7;
            float gi = sG[b][j]      + sBias[j];
            float gf = sG[b][8 + j]  + sBias[8 + j];
            float gg = sG[b][16 + j] + sBias[16 + j];
            float go = sG[b][24 + j] + sBias[24 + j];
            float i_ = 1.f / (1.f + __expf(-gi));
            float f_ = 1.f / (1.f + __expf(-gf));
            float g_ = fast_tanh(gg);
            float o_ = 1.f / (1.f + __expf(-go));
            float c  = f_ * sC[b][j] + i_ * g_;
            sC[b][j] = c;
            ((unsigned short*)&sH[b])[j] = f2bf(o_ * fast_tanh(c));
        }
        __syncthreads();

        // wave 0 publishes the slice with sc1 agent stores, drains vmcnt
        // (orders h-stores before the flag at the coherence point), then
        // lane 0 relaxed-stores the flag.
        if (tid < 64) {
            const unsigned long long* src = (const unsigned long long*)&sH[tid];
            unsigned long long v0 = src[0], v1 = src[1];
            unsigned long long* dst = (unsigned long long*)
                (hbuf + ((size_t)(dec * (T + 1) + t + 1) * B + tid) * H + u0);
            coh_store8(dst, v0);
            coh_store8(dst + 1, v1);
            asm volatile("s_waitcnt vmcnt(0)" ::: "memory");
            if (lane == 0) {
                __hip_atomic_store(myflag, (unsigned)(t + 1), __ATOMIC_RELAXED,
                                   __HIP_MEMORY_SCOPE_AGENT);
            }
        }
    }

    // wait for BOTH decoders to finish everything (output tiles span both)
    {
        if (wave == 0) {
            const unsigned needT = (unsigned)T;
            const unsigned long long* aw = (const unsigned long long*)flags;
            for (;;) {
                unsigned long long w0 = __hip_atomic_load(&aw[lane],      __ATOMIC_RELAXED, __HIP_MEMORY_SCOPE_AGENT);
                unsigned long long w1 = __hip_atomic_load(&aw[64 + lane], __ATOMIC_RELAXED, __HIP_MEMORY_SCOPE_AGENT);
                bool ok = ((unsigned)w0 >= needT) && ((unsigned)(w0 >> 32) >= needT) &&
                          ((unsigned)w1 >= needT) && ((unsigned)(w1 >> 32) >= needT);
                if (__all(ok)) break;
            }
            __builtin_amdgcn_fence(__ATOMIC_ACQUIRE, "agent");   // once per dispatch
        }
        __syncthreads();
    }

    // ---- output projection: Y[dec][t] = h @ W_out^T + b_out ----
    for (int qq = 0; qq < 4; ++qq) {
        int q    = bid * 4 + qq;          // 0 .. 1023
        int ydec = q >> 9;
        int yt   = q & 511;
        const float* bout = ydec ? bbout : fbout;
        const unsigned short* hr = hbuf + ((size_t)(ydec * (T + 1) + yt + 1) * B + m) * H;
        const unsigned short* wb = woutbf + (size_t)ydec * D * H;

        // hoist + cluster the h-row fragments: loaded once, reused for 5 nt tiles
        bf16x8 Ah[32];
        #pragma unroll
        for (int kb = 0; kb < 32; ++kb)
            Ah[kb] = *(const bf16x8*)(hr + kb * 32 + koff);
        __builtin_amdgcn_sched_barrier(0);

        #pragma unroll
        for (int nt = 0; nt < 5; ++nt) {
            f32x4 acc = {0.f, 0.f, 0.f, 0.f};
            const unsigned short* wrow = wb + (size_t)(nt * 16 + l15) * H;
            #pragma unroll 8
            for (int kb = 0; kb < H / 32; ++kb) {
                bf16x8 bf = *(const bf16x8*)(wrow + kb * 32 + koff);
                acc = __builtin_amdgcn_mfma_f32_16x16x32_bf16(Ah[kb], bf, acc, 0, 0, 0);
            }
            float bo = bout[nt * 16 + l15];
            #pragma unroll
            for (int r = 0; r < 4; ++r) {
                int bb_ = wave * 16 + quad * 4 + r;
                out[((size_t)(ydec * T + yt) * B + bb_) * D + nt * 16 + l15] = acc[r] + bo;
            }
        }
    }
}

extern "C" void kernel_launch(void* const* d_in, const int* in_sizes, int n_in,
                              void* d_out, int out_size, void* d_ws, size_t ws_size,
                              hipStream_t stream)
{
    const float* input  = (const float*)d_in[0];
    const float* target = (const float*)d_in[1];
    const float* Win    = (const float*)d_in[2];
    const float* bin    = (const float*)d_in[3];
    const float* fWih   = (const float*)d_in[4];
    const float* fWhh   = (const float*)d_in[5];
    const float* fb     = (const float*)d_in[6];
    const float* fWout  = (const float*)d_in[7];
    const float* fbout  = (const float*)d_in[8];
    const float* bWih   = (const float*)d_in[9];
    const float* bWhh   = (const float*)d_in[10];
    const float* bb     = (const float*)d_in[11];
    const float* bWout  = (const float*)d_in[12];
    const float* bbout  = (const float*)d_in[13];
    float* out = (float*)d_out;

    unsigned short* hbuf  = (unsigned short*)d_ws;
    unsigned short* xsb   = (unsigned short*)((char*)d_ws + HBUF_BYTES);
    unsigned short* wout  = (unsigned short*)((char*)d_ws + HBUF_BYTES + XS_BYTES);
    unsigned int*   flags = (unsigned int*)((char*)d_ws + HBUF_BYTES + XS_BYTES + WOUT_BYTES);

    prep_x0<<<B * D, 64, 0, stream>>>(input, Win, bin, xsb);
    prep_xs<<<(T * B * DP + 255) / 256, 256, 0, stream>>>(target, xsb);
    {
        int n = 2 * D * H + 2 * B * H + NFLAG;
        prep_misc<<<(n + 255) / 256, 256, 0, stream>>>(fWout, bWout, wout, hbuf, flags);
    }

    void* args[] = { &hbuf, &xsb, &wout, &flags,
                     (void*)&fWih, (void*)&fWhh, (void*)&fb,
                     (void*)&bWih, (void*)&bWhh, (void*)&bb,
                     (void*)&fbout, (void*)&bbout, &out };
    hipLaunchCooperativeKernel((void*)lstm_main, dim3(256), dim3(256), args, 0, stream);
}